// Round 7
// baseline (156.767 us; speedup 1.0000x reference)
//
#include <hip/hip_runtime.h>
#include <hip/hip_bf16.h>

// E=32 experts, H=1024 hidden, F=512 ffn, T=1024 tokens, K=8 top-k.
#define NE     32
#define HD     1024
#define FF     512
#define NT     1024
#define TOPK   8
#define NPAIR  (NT * TOPK)      // 8192 routed (token,k) rows
#define MAXT2  96               // max 128-row tiles: 8192/128 + 32

typedef __attribute__((ext_vector_type(8))) short  bf16x8;
typedef __attribute__((ext_vector_type(4))) float  f32x4;

__device__ __forceinline__ unsigned short f2bf_rne(float f) {
    unsigned u = __float_as_uint(f);
    u += 0x7FFFu + ((u >> 16) & 1u);
    return (unsigned short)(u >> 16);
}
__device__ __forceinline__ unsigned pk2(float x, float y) {
    __hip_bfloat162 h = __float22bfloat162_rn(float2{x, y});
    union { __hip_bfloat162 h; unsigned u; } c;
    c.h = h;
    return c.u;
}
__device__ __forceinline__ uint4 pk8q(float4 a, float4 b) {
    uint4 r;
    r.x = pk2(a.x, a.y); r.y = pk2(a.z, a.w);
    r.z = pk2(b.x, b.y); r.w = pk2(b.z, b.w);
    return r;
}
// async global->LDS, 16B per lane; LDS dest = wave-uniform base + lane*16
__device__ __forceinline__ void gload16(const void* g, void* l) {
    __builtin_amdgcn_global_load_lds(
        (const __attribute__((address_space(1))) unsigned int*)g,
        (__attribute__((address_space(3))) unsigned int*)l, 16, 0, 0);
}
// 8 f32 (two swizzled 16B LDS reads) -> bf16x8 fragment
__device__ __forceinline__ bf16x8 pkfrag(const void* p0, const void* p1) {
    f32x4 a = *(const f32x4*)p0;
    f32x4 b = *(const f32x4*)p1;
    union { unsigned u[4]; bf16x8 v; } r;
    r.u[0] = pk2(a[0], a[1]); r.u[1] = pk2(a[2], a[3]);
    r.u[2] = pk2(b[0], b[1]); r.u[3] = pk2(b[2], b[3]);
    return r.v;
}
#define MFMA16(a, b, c) __builtin_amdgcn_mfma_f32_16x16x32_bf16(a, b, c, 0, 0, 0)

// ---------------- workspace layout ----------------
// meta ints: [0]=numt, [1..33]=offsets, [64..159]=tile_e, [160..255]=tile_m,
//            [256..]=tok_list(8192), w_list @ +8448, posmap @ +16640
// bytes: Xg bf16 @128K (8320x1024, 17MB) | A_bf (8320x512, 8.5MB) | O_rows f32 (32MB)
#define OFF_XG (128u * 1024u)
#define OFF_AB (OFF_XG + 8320u * 2048u)
#define OFF_O  (OFF_AB + 8320u * 1024u)

__global__ __launch_bounds__(1024) void k_route(const int* __restrict__ idx,
                                                const float* __restrict__ tkw,
                                                int* __restrict__ meta) {
    __shared__ int sc[NE], scur[NE], soff[NE + 1];
    __shared__ int ste[MAXT2], stm[MAXT2], snt;
    int tid = threadIdx.x;                      // tid == token
    if (tid < NE) { sc[tid] = 0; scur[tid] = 0; }
    __syncthreads();
    int e8[TOPK];
#pragma unroll
    for (int j = 0; j < TOPK; j++) { e8[j] = idx[tid * TOPK + j]; atomicAdd(&sc[e8[j]], 1); }
    __syncthreads();
    if (tid == 0) {
        int off = 0, nt = 0;
        for (int e = 0; e < NE; e++) {
            soff[e] = off;
            for (int s = 0; s < sc[e]; s += 128) { ste[nt] = e; stm[nt] = s; nt++; }
            off += sc[e];
        }
        soff[NE] = off; snt = nt;
    }
    __syncthreads();
    int*   tok_list = meta + 256;
    float* w_list   = (float*)(meta + 8448);
    int*   posmap   = meta + 16640;
#pragma unroll
    for (int j = 0; j < TOPK; j++) {
        int e = e8[j];
        int p = soff[e] + atomicAdd(&scur[e], 1);
        tok_list[p] = tid;
        w_list[p]   = tkw[tid * TOPK + j];
        posmap[tid * TOPK + j] = p;
    }
    if (tid <= NE) meta[1 + tid] = soff[tid];
    if (tid == 0)  meta[0] = snt;
    if (tid < MAXT2) { meta[64 + tid] = (tid < snt) ? ste[tid] : 0;
                       meta[160 + tid] = (tid < snt) ? stm[tid] : 0; }
}

// Pre-gather hs into routed-order bf16 rows: Xg[p][:] = bf16(hs[tok[p]][:])
__global__ void k_gather(const float* __restrict__ hs, const int* __restrict__ meta,
                         unsigned short* __restrict__ Xg) {
    int i = blockIdx.x * blockDim.x + threadIdx.x;   // NPAIR*128 threads
    int p = i >> 7, c = (i & 127) << 3;
    int tok = meta[256 + p];
    float4 a = *(const float4*)(hs + (size_t)tok * HD + c);
    float4 b = *(const float4*)(hs + (size_t)tok * HD + c + 4);
    *(uint4*)(Xg + (size_t)p * HD + c) = pk8q(a, b);
}

// GEMM1: A[row,c] = silu(gate)*up*w_row (bf16). Tile 128 rows x 32 col-pairs.
// 3-buffer LDS pipeline, counted s_waitcnt vmcnt(4), raw s_barrier.
// Per wave per step: 2 X gloads + 2 W gloads = 4 VMEM ops. NO other VMEM in loop.
__global__ __launch_bounds__(256) void k_mm1(
        const unsigned short* __restrict__ Xg, const float* __restrict__ wgu,
        const int* __restrict__ meta, const float* __restrict__ w_list,
        unsigned short* __restrict__ A) {
    int lid = blockIdx.x;                        // 1536 blocks
    int wsw = (lid & 7) * 192 + (lid >> 3);      // XCD chunk (bijective, 1536%8==0)
    int bx = wsw >> 4, by = wsw & 15;            // col-blocks adjacent within chunk
    int numt = meta[0];
    if (bx >= numt) return;
    int e   = meta[64 + bx], m0 = meta[160 + bx];
    int seg = meta[1 + e];
    int nrows = meta[2 + e] - seg - m0;
    if (nrows > 128) nrows = 128;
    int c0 = by * 32;

    __shared__ __align__(16) unsigned char Xs[3][8192];
    __shared__ __align__(16) unsigned char Ws[3][8192];
    int tid = threadIdx.x;
    int wave = tid >> 6, lane = tid & 63, lr = lane & 15, lk = lane >> 4;

    // staging sources (per lane), inverse-swizzled
    const unsigned char* xsrc[2];
    const unsigned char* wsrc[2];
    unsigned ldsoff[2];
#pragma unroll
    for (int i = 0; i < 2; i++) {
        unsigned Lp = (unsigned)(wave * 2 + i) * 1024u + (unsigned)lane * 16u;
        ldsoff[i] = Lp;
        unsigned xr = Lp >> 6, xc = (Lp & 63u) ^ (((Lp >> 7) & 3u) << 4);
        xsrc[i] = (const unsigned char*)Xg + (size_t)(seg + m0 + xr) * (HD * 2) + xc;
        unsigned wr_ = Lp >> 7, wc = (Lp & 127u) ^ ((wr_ & 7u) << 4);
        unsigned grow = (wr_ < 32) ? (c0 + wr_) : (FF + c0 + (wr_ - 32));
        wsrc[i] = (const unsigned char*)wgu + ((size_t)e * (2 * FF) + grow) * (HD * 4) + wc;
    }
    // fragment read offsets (swizzled)
    unsigned aoff[2];
#pragma unroll
    for (int mf = 0; mf < 2; mf++) {
        unsigned row = wave * 32 + mf * 16 + lr;
        aoff[mf] = row * 64 + (((unsigned)lk * 16) ^ (((row >> 1) & 3u) << 4));
    }
    unsigned boff0[4], boff1[4];
#pragma unroll
    for (int nf = 0; nf < 4; nf++) {
        unsigned row = nf * 16 + lr;
        unsigned swz = (row & 7u) << 4;
        boff0[nf] = row * 128 + (((unsigned)lk * 32) ^ swz);
        boff1[nf] = row * 128 + (((unsigned)lk * 32 + 16) ^ swz);
    }

    f32x4 accg[2][2] = {}, accu[2][2] = {};
    // prologue: stage steps 0,1 into buffers 0,1 (8 VMEM outstanding/wave)
#pragma unroll
    for (int i = 0; i < 2; i++) { gload16(xsrc[i], &Xs[0][ldsoff[i]]); gload16(wsrc[i], &Ws[0][ldsoff[i]]); }
#pragma unroll
    for (int i = 0; i < 2; i++) {
        xsrc[i] += 64; wsrc[i] += 128;
        gload16(xsrc[i], &Xs[1][ldsoff[i]]); gload16(wsrc[i], &Ws[1][ldsoff[i]]);
    }

    const int NSTEP = HD / 32;                   // 32
    for (int t = 0; t < NSTEP; ++t) {
        if (t + 1 < NSTEP) asm volatile("s_waitcnt vmcnt(4)" ::: "memory");
        else               asm volatile("s_waitcnt vmcnt(0)" ::: "memory");
        __builtin_amdgcn_s_barrier();
        __builtin_amdgcn_sched_barrier(0);
        if (t + 2 < NSTEP) {                     // issue t+2 into buf[(t+2)%3]
            int nb = (t + 2) % 3;
#pragma unroll
            for (int i = 0; i < 2; i++) {
                xsrc[i] += 64; wsrc[i] += 128;
                gload16(xsrc[i], &Xs[nb][ldsoff[i]]);
                gload16(wsrc[i], &Ws[nb][ldsoff[i]]);
            }
        }
        const unsigned char* xb = Xs[t % 3];
        const unsigned char* wb = Ws[t % 3];
        bf16x8 af0 = *(const bf16x8*)(xb + aoff[0]);
        bf16x8 af1 = *(const bf16x8*)(xb + aoff[1]);
#pragma unroll
        for (int j = 0; j < 2; j++) {
            bf16x8 bg = pkfrag(wb + boff0[j],     wb + boff1[j]);
            bf16x8 bu = pkfrag(wb + boff0[j + 2], wb + boff1[j + 2]);
            accg[0][j] = MFMA16(af0, bg, accg[0][j]);
            accg[1][j] = MFMA16(af1, bg, accg[1][j]);
            accu[0][j] = MFMA16(af0, bu, accu[0][j]);
            accu[1][j] = MFMA16(af1, bu, accu[1][j]);
        }
    }
#pragma unroll
    for (int mf = 0; mf < 2; mf++)
#pragma unroll
        for (int q = 0; q < 4; q++) {
            int r = wave * 32 + mf * 16 + lk * 4 + q;
            if (r < nrows) {
                float w = w_list[seg + m0 + r];
#pragma unroll
                for (int j = 0; j < 2; j++) {
                    float g = accg[mf][j][q], u = accu[mf][j][q];
                    float act = (g / (1.f + __expf(-g))) * u * w;
                    A[(size_t)(seg + m0 + r) * FF + c0 + j * 16 + lr] = f2bf_rne(act);
                }
            }
        }
}

// GEMM2: O_rows[row,n] = A[row,:] . Wd[e][n,:]. Tile 128 rows x 64 out cols.
__global__ __launch_bounds__(256) void k_mm2(
        const unsigned short* __restrict__ A, const float* __restrict__ wd,
        const int* __restrict__ meta, float* __restrict__ O) {
    int lid = blockIdx.x;
    int wsw = (lid & 7) * 192 + (lid >> 3);
    int bx = wsw >> 4, by = wsw & 15;
    int numt = meta[0];
    if (bx >= numt) return;
    int e   = meta[64 + bx], m0 = meta[160 + bx];
    int seg = meta[1 + e];
    int nrows = meta[2 + e] - seg - m0;
    if (nrows > 128) nrows = 128;
    int n0 = by * 64;

    __shared__ __align__(16) unsigned char Xs[3][8192];
    __shared__ __align__(16) unsigned char Ws[3][8192];
    int tid = threadIdx.x;
    int wave = tid >> 6, lane = tid & 63, lr = lane & 15, lk = lane >> 4;

    const unsigned char* xsrc[2];
    const unsigned char* wsrc[2];
    unsigned ldsoff[2];
#pragma unroll
    for (int i = 0; i < 2; i++) {
        unsigned Lp = (unsigned)(wave * 2 + i) * 1024u + (unsigned)lane * 16u;
        ldsoff[i] = Lp;
        unsigned xr = Lp >> 6, xc = (Lp & 63u) ^ (((Lp >> 7) & 3u) << 4);
        xsrc[i] = (const unsigned char*)A + (size_t)(seg + m0 + xr) * (FF * 2) + xc;
        unsigned wr_ = Lp >> 7, wc = (Lp & 127u) ^ ((wr_ & 7u) << 4);
        wsrc[i] = (const unsigned char*)wd + ((size_t)e * HD + n0 + wr_) * (FF * 4) + wc;
    }
    unsigned aoff[2];
#pragma unroll
    for (int mf = 0; mf < 2; mf++) {
        unsigned row = wave * 32 + mf * 16 + lr;
        aoff[mf] = row * 64 + (((unsigned)lk * 16) ^ (((row >> 1) & 3u) << 4));
    }
    unsigned boff0[4], boff1[4];
#pragma unroll
    for (int nf = 0; nf < 4; nf++) {
        unsigned row = nf * 16 + lr;
        unsigned swz = (row & 7u) << 4;
        boff0[nf] = row * 128 + (((unsigned)lk * 32) ^ swz);
        boff1[nf] = row * 128 + (((unsigned)lk * 32 + 16) ^ swz);
    }

    f32x4 acc[2][4] = {};
#pragma unroll
    for (int i = 0; i < 2; i++) { gload16(xsrc[i], &Xs[0][ldsoff[i]]); gload16(wsrc[i], &Ws[0][ldsoff[i]]); }
#pragma unroll
    for (int i = 0; i < 2; i++) {
        xsrc[i] += 64; wsrc[i] += 128;
        gload16(xsrc[i], &Xs[1][ldsoff[i]]); gload16(wsrc[i], &Ws[1][ldsoff[i]]);
    }

    const int NSTEP = FF / 32;                   // 16
    for (int t = 0; t < NSTEP; ++t) {
        if (t + 1 < NSTEP) asm volatile("s_waitcnt vmcnt(4)" ::: "memory");
        else               asm volatile("s_waitcnt vmcnt(0)" ::: "memory");
        __builtin_amdgcn_s_barrier();
        __builtin_amdgcn_sched_barrier(0);
        if (t + 2 < NSTEP) {
            int nb = (t + 2) % 3;
#pragma unroll
            for (int i = 0; i < 2; i++) {
                xsrc[i] += 64; wsrc[i] += 128;
                gload16(xsrc[i], &Xs[nb][ldsoff[i]]);
                gload16(wsrc[i], &Ws[nb][ldsoff[i]]);
            }
        }
        const unsigned char* xb = Xs[t % 3];
        const unsigned char* wb = Ws[t % 3];
        bf16x8 af0 = *(const bf16x8*)(xb + aoff[0]);
        bf16x8 af1 = *(const bf16x8*)(xb + aoff[1]);
#pragma unroll
        for (int nf = 0; nf < 4; nf++) {
            bf16x8 b = pkfrag(wb + boff0[nf], wb + boff1[nf]);
            acc[0][nf] = MFMA16(af0, b, acc[0][nf]);
            acc[1][nf] = MFMA16(af1, b, acc[1][nf]);
        }
    }
#pragma unroll
    for (int mf = 0; mf < 2; mf++)
#pragma unroll
        for (int q = 0; q < 4; q++) {
            int r = wave * 32 + mf * 16 + lk * 4 + q;
            if (r < nrows) {
#pragma unroll
                for (int nf = 0; nf < 4; nf++)
                    O[(size_t)(seg + m0 + r) * HD + n0 + nf * 16 + lr] = acc[mf][nf][q];
            }
        }
}

__global__ void k_reduce(const float* __restrict__ O, const int* __restrict__ posmap,
                         float* __restrict__ out) {
    int i = blockIdx.x * blockDim.x + threadIdx.x;   // over NT*HD/4
    int t = i >> 8, c4 = i & 255;
    float4 acc = make_float4(0.f, 0.f, 0.f, 0.f);
#pragma unroll
    for (int k = 0; k < TOPK; k++) {
        int p = posmap[t * TOPK + k];
        float4 v = ((const float4*)(O + (size_t)p * HD))[c4];
        acc.x += v.x; acc.y += v.y; acc.z += v.z; acc.w += v.w;
    }
    ((float4*)out)[i] = acc;
}

// ============================ launch ============================
extern "C" void kernel_launch(void* const* d_in, const int* in_sizes, int n_in,
                              void* d_out, int out_size, void* d_ws, size_t ws_size,
                              hipStream_t stream) {
    const float* hs  = (const float*)d_in[0];   // (T, H)
    const int*   idx = (const int*)  d_in[1];   // (T, K)
    const float* tkw = (const float*)d_in[2];   // (T, K)
    const float* wgu = (const float*)d_in[3];   // (E, 2F, H)
    const float* wd  = (const float*)d_in[4];   // (E, H, F)
    float* out = (float*)d_out;                 // (T, H)

    char* ws = (char*)d_ws;
    int* meta = (int*)ws;
    unsigned short* Xg   = (unsigned short*)(ws + OFF_XG);
    unsigned short* A_bf = (unsigned short*)(ws + OFF_AB);
    float* O_rows        = (float*)(ws + OFF_O);
    const float* w_list  = (const float*)(meta + 8448);
    const int* posmap    = meta + 16640;

    k_route<<<1, 1024, 0, stream>>>(idx, tkw, meta);
    k_gather<<<NPAIR * (HD / 8) / 256, 256, 0, stream>>>(hs, meta, Xg);
    k_mm1<<<MAXT2 * 16, 256, 0, stream>>>(Xg, wgu, meta, w_list, A_bf);
    k_mm2<<<MAXT2 * 16, 256, 0, stream>>>(A_bf, wd, meta, O_rows);
    k_reduce<<<NT * HD / 4 / 256, 256, 0, stream>>>(O_rows, posmap, out);
}

// Round 8
// 140.644 us; speedup vs baseline: 1.1146x; 1.1146x over previous
//
#include <hip/hip_runtime.h>
#include <hip/hip_bf16.h>

// E=32 experts, H=1024 hidden, F=512 ffn, T=1024 tokens, K=8 top-k.
#define NE     32
#define HD     1024
#define FF     512
#define NT     1024
#define TOPK   8
#define NPAIR  (NT * TOPK)      // 8192 routed (token,k) rows
#define MAXT2  96               // max 128-row tiles

typedef __attribute__((ext_vector_type(8))) short  bf16x8;
typedef __attribute__((ext_vector_type(4))) float  f32x4;

__device__ __forceinline__ unsigned short f2bf_rne(float f) {
    unsigned u = __float_as_uint(f);
    u += 0x7FFFu + ((u >> 16) & 1u);
    return (unsigned short)(u >> 16);
}
__device__ __forceinline__ unsigned pk2(float x, float y) {
    __hip_bfloat162 h = __float22bfloat162_rn(float2{x, y});
    union { __hip_bfloat162 h; unsigned u; } c;
    c.h = h;
    return c.u;
}
__device__ __forceinline__ uint4 pk8q(float4 a, float4 b) {
    uint4 r;
    r.x = pk2(a.x, a.y); r.y = pk2(a.z, a.w);
    r.z = pk2(b.x, b.y); r.w = pk2(b.z, b.w);
    return r;
}
// 8 f32 in regs -> bf16x8 fragment
__device__ __forceinline__ bf16x8 pk8r(float4 a, float4 b) {
    union { unsigned u[4]; bf16x8 v; } r;
    r.u[0] = pk2(a.x, a.y); r.u[1] = pk2(a.z, a.w);
    r.u[2] = pk2(b.x, b.y); r.u[3] = pk2(b.z, b.w);
    return r.v;
}
// async global->LDS, 16B per lane; LDS dest = wave-uniform base + lane*16
__device__ __forceinline__ void gload16(const void* g, void* l) {
    __builtin_amdgcn_global_load_lds(
        (const __attribute__((address_space(1))) unsigned int*)g,
        (__attribute__((address_space(3))) unsigned int*)l, 16, 0, 0);
}
#define MFMA16(a, b, c) __builtin_amdgcn_mfma_f32_16x16x32_bf16(a, b, c, 0, 0, 0)

// per-K-step sync: wait own X(t) gloads (exactly 6 younger VMEM ops may remain),
// workgroup barrier, then fence the scheduler (rule #18).
#define PIPE_SYNC() do {                                   \
    asm volatile("s_waitcnt vmcnt(6)" ::: "memory");       \
    __builtin_amdgcn_s_barrier();                          \
    __builtin_amdgcn_sched_barrier(0);                     \
} while (0)

// ---------------- workspace layout ----------------
// meta ints: [0]=numt, [1..33]=offsets, [64..159]=tile_e, [160..255]=tile_m,
//            [256..]=tok_list(8192), w_list @ +8448, posmap @ +16640
// bytes: Xg bf16 @128K (8320x1024) | A_bf (8320x512) | O_rows f32 (32MB)
#define OFF_XG (128u * 1024u)
#define OFF_AB (OFF_XG + 8320u * 2048u)
#define OFF_O  (OFF_AB + 8320u * 1024u)

__global__ __launch_bounds__(1024) void k_route(const int* __restrict__ idx,
                                                const float* __restrict__ tkw,
                                                int* __restrict__ meta) {
    __shared__ int sc[NE], scur[NE], soff[NE + 1];
    __shared__ int ste[MAXT2], stm[MAXT2], snt;
    int tid = threadIdx.x;                      // tid == token
    if (tid < NE) { sc[tid] = 0; scur[tid] = 0; }
    __syncthreads();
    int e8[TOPK];
#pragma unroll
    for (int j = 0; j < TOPK; j++) { e8[j] = idx[tid * TOPK + j]; atomicAdd(&sc[e8[j]], 1); }
    __syncthreads();
    if (tid == 0) {
        int off = 0, nt = 0;
        for (int e = 0; e < NE; e++) {
            soff[e] = off;
            for (int s = 0; s < sc[e]; s += 128) { ste[nt] = e; stm[nt] = s; nt++; }
            off += sc[e];
        }
        soff[NE] = off; snt = nt;
    }
    __syncthreads();
    int*   tok_list = meta + 256;
    float* w_list   = (float*)(meta + 8448);
    int*   posmap   = meta + 16640;
#pragma unroll
    for (int j = 0; j < TOPK; j++) {
        int e = e8[j];
        int p = soff[e] + atomicAdd(&scur[e], 1);
        tok_list[p] = tid;
        w_list[p]   = tkw[tid * TOPK + j];
        posmap[tid * TOPK + j] = p;
    }
    if (tid <= NE) meta[1 + tid] = soff[tid];
    if (tid == 0)  meta[0] = snt;
    if (tid < MAXT2) { meta[64 + tid] = (tid < snt) ? ste[tid] : 0;
                       meta[160 + tid] = (tid < snt) ? stm[tid] : 0; }
}

// Pre-gather hs into routed-order bf16 rows: Xg[p][:] = bf16(hs[tok[p]][:])
__global__ void k_gather(const float* __restrict__ hs, const int* __restrict__ meta,
                         unsigned short* __restrict__ Xg) {
    int i = blockIdx.x * blockDim.x + threadIdx.x;   // NPAIR*128 threads
    int p = i >> 7, c = (i & 127) << 3;
    int tok = meta[256 + p];
    float4 a = *(const float4*)(hs + (size_t)tok * HD + c);
    float4 b = *(const float4*)(hs + (size_t)tok * HD + c + 4);
    *(uint4*)(Xg + (size_t)p * HD + c) = pk8q(a, b);
}

// GEMM1: A[row,cp] = silu(gate)*up*w_row (bf16).
// Tile M=128 x N=64 colpairs; 4 waves N-split (16 cp each); BK=32, 32 steps.
// X: bf16 LDS, gload_lds 3-buffer 2-ahead.  W: f32 global -> regs (1 ahead) -> cvt.
__global__ __launch_bounds__(256, 2) void k_mm1(
        const unsigned short* __restrict__ Xg, const float* __restrict__ wgu,
        const int* __restrict__ meta, const float* __restrict__ w_list,
        unsigned short* __restrict__ A) {
    int lid = blockIdx.x;                        // 768 blocks
    int wsw = (lid & 7) * 96 + (lid >> 3);       // XCD swizzle (768%8==0)
    int bx = wsw >> 3, by = wsw & 7;
    int numt = meta[0];
    if (bx >= numt) return;
    int e   = meta[64 + bx], m0 = meta[160 + bx];
    int seg = meta[1 + e];
    int nrows = meta[2 + e] - seg - m0;
    if (nrows > 128) nrows = 128;
    int c0 = by * 64;                            // 64 colpairs per block

    __shared__ __align__(16) unsigned char Xb0[8192];
    __shared__ __align__(16) unsigned char Xb1[8192];
    __shared__ __align__(16) unsigned char Xb2[8192];
    int tid = threadIdx.x;
    int wave = tid >> 6, lane = tid & 63, lr = lane & 15, lk = lane >> 4;

    // X staging (2 gloads/wave/step), inverse-swizzled source
    unsigned Lp0 = (unsigned)(wave * 2) * 1024u + (unsigned)lane * 16u;
    unsigned Lp1 = Lp0 + 1024u;
    unsigned ldsoff0 = Lp0, ldsoff1 = Lp1;
    const unsigned char* xsrc0 = (const unsigned char*)Xg +
        (size_t)(seg + m0 + (Lp0 >> 6)) * (HD * 2) + ((Lp0 & 63u) ^ (((Lp0 >> 7) & 3u) << 4));
    const unsigned char* xsrc1 = (const unsigned char*)Xg +
        (size_t)(seg + m0 + (Lp1 >> 6)) * (HD * 2) + ((Lp1 & 63u) ^ (((Lp1 >> 7) & 3u) << 4));

    // W pointers: this wave's 16 colpairs; per lane one gate row + one up row
    int cp = c0 + wave * 16 + lr;
    const float* gp = wgu + ((size_t)e * 2 * FF + cp) * HD + lk * 8;
    const float* up = gp + (size_t)FF * HD;

    // A-fragment LDS read offsets (swizzled), rows mf*16+lr
    unsigned aoff[8];
#pragma unroll
    for (int mf = 0; mf < 8; mf++) {
        unsigned row = mf * 16 + lr;
        aoff[mf] = row * 64 + (((unsigned)lk * 16) ^ (((row >> 1) & 3u) << 4));
    }

    f32x4 acc[8][2] = {};
    float4 wsA[4], wsB[4];
    const unsigned char* cur = Xb0;
    const unsigned char* nxt = Xb1;
    const unsigned char* fut = Xb2;

    // prologue: X(0)->b0, X(1)->b1 in flight; W(0)->setA
    gload16(xsrc0, Xb0 + ldsoff0); gload16(xsrc1, Xb0 + ldsoff1);
    xsrc0 += 64; xsrc1 += 64;
    gload16(xsrc0, Xb1 + ldsoff0); gload16(xsrc1, Xb1 + ldsoff1);
    xsrc0 += 64; xsrc1 += 64;
    wsA[0] = *(const float4*)(gp);     wsA[1] = *(const float4*)(gp + 4);
    wsA[2] = *(const float4*)(up);     wsA[3] = *(const float4*)(up + 4);
    int wk = 32;

    auto step = [&](float4 (&wuse)[4], float4 (&wld)[4], bool doX, bool doW) {
        PIPE_SYNC();
        if (doX) {                      // issue X(t+2) -> fut
            gload16(xsrc0, (void*)(fut + ldsoff0));
            gload16(xsrc1, (void*)(fut + ldsoff1));
            xsrc0 += 64; xsrc1 += 64;
        }
        if (doW) {                      // issue W(t+1) -> other reg set
            wld[0] = *(const float4*)(gp + wk);     wld[1] = *(const float4*)(gp + wk + 4);
            wld[2] = *(const float4*)(up + wk);     wld[3] = *(const float4*)(up + wk + 4);
            wk += 32;
        }
        bf16x8 bg = pk8r(wuse[0], wuse[1]);
        bf16x8 bu = pk8r(wuse[2], wuse[3]);
#pragma unroll
        for (int mf = 0; mf < 8; mf++) {
            bf16x8 af = *(const bf16x8*)(cur + aoff[mf]);
            acc[mf][0] = MFMA16(af, bg, acc[mf][0]);
            acc[mf][1] = MFMA16(af, bu, acc[mf][1]);
        }
        const unsigned char* t = cur; cur = nxt; nxt = fut; fut = t;
    };

    for (int t2 = 0; t2 < 14; t2++) {   // t = 0..27, all full
        step(wsA, wsB, true, true);
        step(wsB, wsA, true, true);
    }
    step(wsA, wsB, true,  true);        // t=28: X(30), W(29)->B
    step(wsB, wsA, true,  true);        // t=29: X(31), W(30)->A
    step(wsA, wsB, false, true);        // t=30: W(31)->B
    step(wsB, wsA, false, false);       // t=31

    // epilogue: silu(gate)*up*w -> bf16 A
#pragma unroll
    for (int mf = 0; mf < 8; mf++)
#pragma unroll
        for (int q = 0; q < 4; q++) {
            int r = mf * 16 + lk * 4 + q;
            if (r < nrows) {
                float w = w_list[seg + m0 + r];
                float g = acc[mf][0][q], u = acc[mf][1][q];
                float act = (g / (1.f + __expf(-g))) * u * w;
                A[(size_t)(seg + m0 + r) * FF + cp] = f2bf_rne(act);
            }
        }
}

// GEMM2: O_rows[row,n] = A[row,:] . Wd[e][n,:].
// Tile M=128 x N=128; 4 waves N-split (32 each); BK=32, 16 steps.
__global__ __launch_bounds__(256, 2) void k_mm2(
        const unsigned short* __restrict__ A, const float* __restrict__ wd,
        const int* __restrict__ meta, float* __restrict__ O) {
    int lid = blockIdx.x;                        // 768 blocks
    int wsw = (lid & 7) * 96 + (lid >> 3);
    int bx = wsw >> 3, by = wsw & 7;
    int numt = meta[0];
    if (bx >= numt) return;
    int e   = meta[64 + bx], m0 = meta[160 + bx];
    int seg = meta[1 + e];
    int nrows = meta[2 + e] - seg - m0;
    if (nrows > 128) nrows = 128;
    int n0 = by * 128;

    __shared__ __align__(16) unsigned char Xb0[8192];
    __shared__ __align__(16) unsigned char Xb1[8192];
    __shared__ __align__(16) unsigned char Xb2[8192];
    int tid = threadIdx.x;
    int wave = tid >> 6, lane = tid & 63, lr = lane & 15, lk = lane >> 4;

    unsigned Lp0 = (unsigned)(wave * 2) * 1024u + (unsigned)lane * 16u;
    unsigned Lp1 = Lp0 + 1024u;
    unsigned ldsoff0 = Lp0, ldsoff1 = Lp1;
    const unsigned char* xsrc0 = (const unsigned char*)A +
        (size_t)(seg + m0 + (Lp0 >> 6)) * (FF * 2) + ((Lp0 & 63u) ^ (((Lp0 >> 7) & 3u) << 4));
    const unsigned char* xsrc1 = (const unsigned char*)A +
        (size_t)(seg + m0 + (Lp1 >> 6)) * (FF * 2) + ((Lp1 & 63u) ^ (((Lp1 >> 7) & 3u) << 4));

    // W: this wave's 32 out-cols (2 nf x 16); per lane rows n0+wave*32+{0,16}+lr
    int n_a = n0 + wave * 32 + lr;
    int n_b = n_a + 16;
    const float* wpa = wd + ((size_t)e * HD + n_a) * FF + lk * 8;
    const float* wpb = wd + ((size_t)e * HD + n_b) * FF + lk * 8;

    unsigned aoff[8];
#pragma unroll
    for (int mf = 0; mf < 8; mf++) {
        unsigned row = mf * 16 + lr;
        aoff[mf] = row * 64 + (((unsigned)lk * 16) ^ (((row >> 1) & 3u) << 4));
    }

    f32x4 acc[8][2] = {};
    float4 wsA[4], wsB[4];
    const unsigned char* cur = Xb0;
    const unsigned char* nxt = Xb1;
    const unsigned char* fut = Xb2;

    gload16(xsrc0, Xb0 + ldsoff0); gload16(xsrc1, Xb0 + ldsoff1);
    xsrc0 += 64; xsrc1 += 64;
    gload16(xsrc0, Xb1 + ldsoff0); gload16(xsrc1, Xb1 + ldsoff1);
    xsrc0 += 64; xsrc1 += 64;
    wsA[0] = *(const float4*)(wpa);    wsA[1] = *(const float4*)(wpa + 4);
    wsA[2] = *(const float4*)(wpb);    wsA[3] = *(const float4*)(wpb + 4);
    int wk = 32;

    auto step = [&](float4 (&wuse)[4], float4 (&wld)[4], bool doX, bool doW) {
        PIPE_SYNC();
        if (doX) {
            gload16(xsrc0, (void*)(fut + ldsoff0));
            gload16(xsrc1, (void*)(fut + ldsoff1));
            xsrc0 += 64; xsrc1 += 64;
        }
        if (doW) {
            wld[0] = *(const float4*)(wpa + wk);   wld[1] = *(const float4*)(wpa + wk + 4);
            wld[2] = *(const float4*)(wpb + wk);   wld[3] = *(const float4*)(wpb + wk + 4);
            wk += 32;
        }
        bf16x8 b0 = pk8r(wuse[0], wuse[1]);
        bf16x8 b1 = pk8r(wuse[2], wuse[3]);
#pragma unroll
        for (int mf = 0; mf < 8; mf++) {
            bf16x8 af = *(const bf16x8*)(cur + aoff[mf]);
            acc[mf][0] = MFMA16(af, b0, acc[mf][0]);
            acc[mf][1] = MFMA16(af, b1, acc[mf][1]);
        }
        const unsigned char* t = cur; cur = nxt; nxt = fut; fut = t;
    };

    for (int t2 = 0; t2 < 6; t2++) {    // t = 0..11
        step(wsA, wsB, true, true);
        step(wsB, wsA, true, true);
    }
    step(wsA, wsB, true,  true);        // t=12: X(14), W(13)->B
    step(wsB, wsA, true,  true);        // t=13: X(15), W(14)->A
    step(wsA, wsB, false, true);        // t=14: W(15)->B
    step(wsB, wsA, false, false);       // t=15

#pragma unroll
    for (int mf = 0; mf < 8; mf++)
#pragma unroll
        for (int q = 0; q < 4; q++) {
            int r = mf * 16 + lk * 4 + q;
            if (r < nrows) {
                O[(size_t)(seg + m0 + r) * HD + n_a] = acc[mf][0][q];
                O[(size_t)(seg + m0 + r) * HD + n_b] = acc[mf][1][q];
            }
        }
}

__global__ void k_reduce(const float* __restrict__ O, const int* __restrict__ posmap,
                         float* __restrict__ out) {
    int i = blockIdx.x * blockDim.x + threadIdx.x;   // over NT*HD/4
    int t = i >> 8, c4 = i & 255;
    float4 acc = make_float4(0.f, 0.f, 0.f, 0.f);
#pragma unroll
    for (int k = 0; k < TOPK; k++) {
        int p = posmap[t * TOPK + k];
        float4 v = ((const float4*)(O + (size_t)p * HD))[c4];
        acc.x += v.x; acc.y += v.y; acc.z += v.z; acc.w += v.w;
    }
    ((float4*)out)[i] = acc;
}

// ============================ launch ============================
extern "C" void kernel_launch(void* const* d_in, const int* in_sizes, int n_in,
                              void* d_out, int out_size, void* d_ws, size_t ws_size,
                              hipStream_t stream) {
    const float* hs  = (const float*)d_in[0];   // (T, H)
    const int*   idx = (const int*)  d_in[1];   // (T, K)
    const float* tkw = (const float*)d_in[2];   // (T, K)
    const float* wgu = (const float*)d_in[3];   // (E, 2F, H)
    const float* wd  = (const float*)d_in[4];   // (E, H, F)
    float* out = (float*)d_out;                 // (T, H)

    char* ws = (char*)d_ws;
    int* meta = (int*)ws;
    unsigned short* Xg   = (unsigned short*)(ws + OFF_XG);
    unsigned short* A_bf = (unsigned short*)(ws + OFF_AB);
    float* O_rows        = (float*)(ws + OFF_O);
    const float* w_list  = (const float*)(meta + 8448);
    const int* posmap    = meta + 16640;

    k_route<<<1, 1024, 0, stream>>>(idx, tkw, meta);
    k_gather<<<NPAIR * (HD / 8) / 256, 256, 0, stream>>>(hs, meta, Xg);
    k_mm1<<<MAXT2 * 8, 256, 0, stream>>>(Xg, wgu, meta, w_list, A_bf);
    k_mm2<<<MAXT2 * 8, 256, 0, stream>>>(A_bf, wd, meta, O_rows);
    k_reduce<<<NT * HD / 4 / 256, 256, 0, stream>>>(O_rows, posmap, out);
}